// Round 1
// baseline (182.111 us; speedup 1.0000x reference)
//
#include <hip/hip_runtime.h>
#include <math.h>

typedef float f4 __attribute__((ext_vector_type(4)));
typedef float f32x4 __attribute__((ext_vector_type(4)));
typedef _Float16 h4 __attribute__((ext_vector_type(4)));
typedef _Float16 h8 __attribute__((ext_vector_type(8)));

#define BH 32
#define NN 4096
#define DD 64
#define FF 256
#define EE 64
#define SPLITS 8
#define ROWS_K 512
#define QB 8
#define ROWS_Q 512
#define ST 72    // Pt stride (f16)
#define SK 136   // kside kpt/vt row stride (128 rows + 8 pad)
#define STF 264  // qside qpt/kvt stride (256 + 8 pad)

#define MFMA(a, b, c) __builtin_amdgcn_mfma_f32_16x16x32_f16((a), (b), (c), 0, 0, 0)

__device__ inline h8 cvt2(f4 x0, f4 x1) {
  h8 r;
  r[0] = (_Float16)x0.x; r[1] = (_Float16)x0.y;
  r[2] = (_Float16)x0.z; r[3] = (_Float16)x0.w;
  r[4] = (_Float16)x1.x; r[5] = (_Float16)x1.y;
  r[6] = (_Float16)x1.z; r[7] = (_Float16)x1.w;
  return r;
}

// ---------------------------------------------------------------------------
// kside: grid 32*8, 1024 thr (16 waves, 4 waves/SIMD). Wave pair (s = w>>1,
// h = w&1) co-owns a 16-row strip and splits the 256 features in half.
// Full row-max (semantically required) via 1KB LDS pair-exchange.
// 3 barriers per 128-row tile. kv GEMM: wave owns one 16-f slice.
// ---------------------------------------------------------------------------
__global__ __launch_bounds__(1024, 4) void fa_kside(
    const float* __restrict__ kin, const float* __restrict__ vin,
    const float* __restrict__ P, float* __restrict__ kv_part,
    float* __restrict__ ksum_part) {
  __shared__ _Float16 Pt[FF * ST];    // 36.9 KB  P^T[f][d]
  __shared__ _Float16 kpt[FF * SK];   // 69.6 KB  kp^T[f][row]
  __shared__ _Float16 vt[EE * SK];    // 17.4 KB  v^T[e][row]
  __shared__ float mx_lds[8 * 32];    // 1 KB   per-strip half-maxes
  __shared__ float ks_lds[16 * 128];  // 8 KB

  const int t = threadIdx.x;
  const int w = t >> 6, lane = t & 63;
  const int g = lane >> 4, fl = lane & 15;
  const int s = w >> 1, h = w & 1;
  const int bh = blockIdx.x >> 3, split = blockIdx.x & 7;
  const int bhs = blockIdx.x;
  const int k0 = g * 8;
  const int fbase = h * 128;

  {  // stage P^T (f16)
    const f4* Pg4 = (const f4*)P;
#pragma unroll
    for (int i = 0; i < 4; ++i) {
      int idx = t + i * 1024;
      f4 pv = Pg4[idx];
      int d = idx >> 6, f0 = (idx & 63) * 4;
      Pt[(f0 + 0) * ST + d] = (_Float16)pv.x;
      Pt[(f0 + 1) * ST + d] = (_Float16)pv.y;
      Pt[(f0 + 2) * ST + d] = (_Float16)pv.z;
      Pt[(f0 + 3) * ST + d] = (_Float16)pv.w;
    }
  }

  f32x4 kvacc[4];
#pragma unroll
  for (int nt = 0; nt < 4; ++nt) kvacc[nt] = (f32x4){0.f, 0.f, 0.f, 0.f};
  float ksum_acc[8];
#pragma unroll
  for (int T = 0; T < 8; ++T) ksum_acc[T] = 0.f;

  const size_t base = (size_t)bh * NN * DD + (size_t)split * ROWS_K * DD;
  __syncthreads();  // Pt ready

  for (int tile = 0; tile < 4; ++tile) {
    if (tile) __syncthreads();  // WAR: previous GEMM reads of kpt/vt done
    const int r0 = tile * 128;

    // A fragments of k directly from global (pair waves duplicate; L1-hit)
    const float* krow = kin + base + (size_t)(r0 + s * 16 + fl) * DD;
    h8 a0 = cvt2(*(const f4*)&krow[k0], *(const f4*)&krow[k0 + 4]);
    h8 a1 = cvt2(*(const f4*)&krow[32 + k0], *(const f4*)&krow[32 + k0 + 4]);

    // v^T staging: each of 16 waves stages 8 rows, lane owns e=lane
    {
      const float* vb = vin + base + (size_t)(r0 + w * 8) * DD + lane;
      h8 tv;
#pragma unroll
      for (int j = 0; j < 8; ++j) tv[j] = (_Float16)vb[j * DD];
      *(h8*)&vt[lane * SK + w * 8] = tv;
    }

    // projection: this wave's 128-feature half for its strip
    f32x4 lac[8];
#pragma unroll
    for (int T = 0; T < 8; ++T) {
      int ncol = fbase + T * 16 + fl;
      h8 b0 = *(const h8*)&Pt[ncol * ST + k0];
      h8 b1 = *(const h8*)&Pt[ncol * ST + 32 + k0];
      f32x4 c = {0.f, 0.f, 0.f, 0.f};
      c = MFMA(a0, b0, c);
      c = MFMA(a1, b1, c);
      lac[T] = c;
    }

    // own-half rowmax, then pair-exchange through LDS for the full-256 max
    float mrow[4];
#pragma unroll
    for (int rg = 0; rg < 4; ++rg) {
      float m = lac[0][rg];
#pragma unroll
      for (int T = 1; T < 8; ++T) m = fmaxf(m, lac[T][rg]);
#pragma unroll
      for (int off = 1; off <= 8; off <<= 1)
        m = fmaxf(m, __shfl_xor(m, off, 64));
      mrow[rg] = m;
    }
    if (fl == 0) {
#pragma unroll
      for (int rg = 0; rg < 4; ++rg)
        mx_lds[s * 32 + h * 16 + g * 4 + rg] = mrow[rg];
    }
    __syncthreads();  // half-maxes ready (vt also complete here)
#pragma unroll
    for (int rg = 0; rg < 4; ++rg)
      mrow[rg] = fmaxf(mrow[rg], mx_lds[s * 32 + (1 - h) * 16 + g * 4 + rg]);

    // exp + kp^T write + ksum accumulate (own feature half)
#pragma unroll
    for (int T = 0; T < 8; ++T) {
      int ncol = fbase + T * 16 + fl;
      h4 kp;
#pragma unroll
      for (int rg = 0; rg < 4; ++rg) {
        float ev = __expf(lac[T][rg] - mrow[rg]) * 0.0625f;
        _Float16 hv = (_Float16)ev;
        ksum_acc[T] += (float)hv;
        kp[rg] = hv;
      }
      *(h4*)&kpt[ncol * SK + s * 16 + g * 4] = kp;
    }
    __syncthreads();  // kpt ready

    // kv GEMM: wave owns f-tile w (16 f) x 4 e-tiles, k = 128 rows
#pragma unroll
    for (int kst = 0; kst < 4; ++kst) {
      h8 vbf[4];
#pragma unroll
      for (int nt = 0; nt < 4; ++nt)
        vbf[nt] = *(const h8*)&vt[(nt * 16 + fl) * SK + kst * 32 + k0];
      h8 ka = *(const h8*)&kpt[(w * 16 + fl) * SK + kst * 32 + k0];
#pragma unroll
      for (int nt = 0; nt < 4; ++nt)
        kvacc[nt] = MFMA(ka, vbf[nt], kvacc[nt]);
    }
  }

  // write kv partial
  float* kvp = kv_part + (size_t)bhs * (FF * EE);
#pragma unroll
  for (int nt = 0; nt < 4; ++nt)
#pragma unroll
    for (int rg = 0; rg < 4; ++rg) {
      int f = w * 16 + g * 4 + rg;
      int e = nt * 16 + fl;
      kvp[f * EE + e] = kvacc[nt][rg];
    }

  // ksum partial: reduce over g in-wave, then cross-wave via LDS
#pragma unroll
  for (int T = 0; T < 8; ++T) {
    float sv = ksum_acc[T];
    sv += __shfl_xor(sv, 16, 64);
    sv += __shfl_xor(sv, 32, 64);
    if (lane < 16) ks_lds[w * 128 + T * 16 + lane] = sv;
  }
  __syncthreads();
  if (t < FF) {
    int hh = t >> 7, inner = t & 127;
    float sv = 0.f;
#pragma unroll
    for (int si = 0; si < 8; ++si) sv += ks_lds[(si * 2 + hh) * 128 + inner];
    ksum_part[(size_t)bhs * FF + t] = sv;
  }
}

// ---------------------------------------------------------------------------
// reduce: 544 blocks x 256 thr. Blocks 0..511: one (bh, 16-f-slice) each,
// vectorized sum + LDS transpose -> kvt f16 [e][f]. Blocks 512..543: ksum.
// ---------------------------------------------------------------------------
__global__ __launch_bounds__(256) void fa_reduce(
    const float* __restrict__ kv_part, const float* __restrict__ ksum_part,
    _Float16* __restrict__ kvt_g, float* __restrict__ ksum_g) {
  __shared__ _Float16 tl[EE * 18];
  const int b = blockIdx.x, t = threadIdx.x;
  if (b < 512) {
    const int bh = b >> 4, c = b & 15;
#pragma unroll
    for (int i = 0; i < 4; ++i) {
      int idx = i * 256 + t;
      int fr = idx >> 6, e = idx & 63;
      float s = 0.f;
#pragma unroll
      for (int sp = 0; sp < SPLITS; ++sp)
        s += kv_part[(size_t)(bh * SPLITS + sp) * (FF * EE) + (c * 16 + fr) * EE + e];
      tl[e * 18 + fr] = (_Float16)s;
    }
    __syncthreads();
    unsigned int* og = (unsigned int*)kvt_g + (size_t)bh * 8192;
#pragma unroll
    for (int i = 0; i < 2; ++i) {
      int idx = i * 256 + t;
      int e = idx >> 3, fp = (idx & 7) * 2;
      og[e * 128 + c * 8 + (idx & 7)] = *(unsigned int*)&tl[e * 18 + fp];
    }
  } else {
    const int bh = b - 512;
    float s = 0.f;
#pragma unroll
    for (int sp = 0; sp < SPLITS; ++sp)
      s += ksum_part[(size_t)(bh * SPLITS + sp) * FF + t];
    ksum_g[bh * FF + t] = s + 1e-6f;
  }
}

// ---------------------------------------------------------------------------
// qside: grid 32*8, 1024 thr (16 waves). Wave pair (s,h) co-owns a 16-row
// strip, splits features. Consistent per-row scale via max pair-exchange
// (cancels exactly in out/denom ratio); denominator halves summed via LDS.
// Out GEMM split by e-tiles across the pair. 3 barriers per 128-row strip.
// ---------------------------------------------------------------------------
__global__ __launch_bounds__(1024, 4) void fa_qside(
    const float* __restrict__ qin, const float* __restrict__ P,
    const _Float16* __restrict__ kvt_g, const float* __restrict__ ksum_g,
    float* __restrict__ out) {
  __shared__ _Float16 Pt[FF * ST];        // 36.9 KB
  __shared__ _Float16 kvt[EE * STF];      // 33.8 KB kv^T[e][f]
  __shared__ _Float16 qpt[8 * 16 * STF];  // 67.6 KB strip-shared qp[row][f]
  __shared__ float mx_lds[8 * 32];        // 1 KB
  __shared__ float den_lds[8 * 32];       // 1 KB

  const int t = threadIdx.x;
  const int w = t >> 6, lane = t & 63;
  const int g = lane >> 4, fl = lane & 15;
  const int s = w >> 1, h = w & 1;
  const int bh = blockIdx.x >> 3, qb = blockIdx.x & 7;
  const int k0 = g * 8;
  const int fbase = h * 128;

  {  // stage P^T
    const f4* Pg4 = (const f4*)P;
#pragma unroll
    for (int i = 0; i < 4; ++i) {
      int idx = t + i * 1024;
      f4 pv = Pg4[idx];
      int d = idx >> 6, f0 = (idx & 63) * 4;
      Pt[(f0 + 0) * ST + d] = (_Float16)pv.x;
      Pt[(f0 + 1) * ST + d] = (_Float16)pv.y;
      Pt[(f0 + 2) * ST + d] = (_Float16)pv.z;
      Pt[(f0 + 3) * ST + d] = (_Float16)pv.w;
    }
  }
  {  // stage kv^T
    const h8* src = (const h8*)(kvt_g + (size_t)bh * FF * EE);
#pragma unroll
    for (int i = 0; i < 2; ++i) {
      int idx = t + i * 1024;
      int e = idx >> 5, f0 = (idx & 31) * 8;
      *(h8*)&kvt[e * STF + f0] = src[idx];
    }
  }
  float ksr[8];
#pragma unroll
  for (int T = 0; T < 8; ++T)
    ksr[T] = ksum_g[bh * FF + fbase + T * 16 + fl];
  __syncthreads();

  _Float16* myqpt = qpt + s * 16 * STF;
  const size_t base = (size_t)bh * NN * DD + (size_t)qb * ROWS_Q * DD;
  float* ob = out + (size_t)bh * NN * EE + (size_t)qb * ROWS_Q * EE;

  for (int st = 0; st < 4; ++st) {
    if (st) __syncthreads();  // WAR: previous out GEMM reads of qpt done
    const int r0 = st * 128;
    const float* qrow = qin + base + (size_t)(r0 + s * 16 + fl) * DD;
    h8 a0 = cvt2(*(const f4*)&qrow[k0], *(const f4*)&qrow[k0 + 4]);
    h8 a1 = cvt2(*(const f4*)&qrow[32 + k0], *(const f4*)&qrow[32 + k0 + 4]);

    f32x4 lac[8];
#pragma unroll
    for (int T = 0; T < 8; ++T) {
      int ncol = fbase + T * 16 + fl;
      h8 b0 = *(const h8*)&Pt[ncol * ST + k0];
      h8 b1 = *(const h8*)&Pt[ncol * ST + 32 + k0];
      f32x4 c = {0.f, 0.f, 0.f, 0.f};
      c = MFMA(a0, b0, c);
      c = MFMA(a1, b1, c);
      lac[T] = c;
    }

    float mrow[4];
#pragma unroll
    for (int rg = 0; rg < 4; ++rg) {
      float m = lac[0][rg];
#pragma unroll
      for (int T = 1; T < 8; ++T) m = fmaxf(m, lac[T][rg]);
#pragma unroll
      for (int off = 1; off <= 8; off <<= 1)
        m = fmaxf(m, __shfl_xor(m, off, 64));
      mrow[rg] = m;
    }
    if (fl == 0) {
#pragma unroll
      for (int rg = 0; rg < 4; ++rg)
        mx_lds[s * 32 + h * 16 + g * 4 + rg] = mrow[rg];
    }
    __syncthreads();  // half-maxes ready
#pragma unroll
    for (int rg = 0; rg < 4; ++rg)
      mrow[rg] = fmaxf(mrow[rg], mx_lds[s * 32 + (1 - h) * 16 + g * 4 + rg]);

    float den[4] = {0.f, 0.f, 0.f, 0.f};
#pragma unroll
    for (int T = 0; T < 8; ++T) {
      int ncol = fbase + T * 16 + fl;
#pragma unroll
      for (int rg = 0; rg < 4; ++rg) {
        float ev = __expf(lac[T][rg] - mrow[rg]) * 0.0625f;
        _Float16 hv = (_Float16)ev;
        den[rg] += (float)hv * ksr[T];
        myqpt[(g * 4 + rg) * STF + ncol] = hv;
      }
    }
#pragma unroll
    for (int rg = 0; rg < 4; ++rg) {
#pragma unroll
      for (int off = 1; off <= 8; off <<= 1)
        den[rg] += __shfl_xor(den[rg], off, 64);
    }
    if (fl == 0) {
#pragma unroll
      for (int rg = 0; rg < 4; ++rg)
        den_lds[s * 32 + h * 16 + g * 4 + rg] = den[rg];
    }
    __syncthreads();  // qpt (both halves) + den halves ready

    float inv[4];
#pragma unroll
    for (int rg = 0; rg < 4; ++rg) {
      float dtot = den_lds[s * 32 + g * 4 + rg] + den_lds[s * 32 + 16 + g * 4 + rg];
      inv[rg] = 1.0f / dtot;
    }

    // out GEMM: A = strip qp (full 256 f), B = kvt; pair splits e-tiles
    f32x4 oacc[2];
#pragma unroll
    for (int n2 = 0; n2 < 2; ++n2) oacc[n2] = (f32x4){0.f, 0.f, 0.f, 0.f};
#pragma unroll
    for (int kst = 0; kst < 8; ++kst) {
      h8 aq = *(const h8*)&myqpt[fl * STF + kst * 32 + k0];
#pragma unroll
      for (int n2 = 0; n2 < 2; ++n2) {
        h8 bq = *(const h8*)&kvt[((h * 2 + n2) * 16 + fl) * STF + kst * 32 + k0];
        oacc[n2] = MFMA(aq, bq, oacc[n2]);
      }
    }

    float* obt = ob + (size_t)(r0 + s * 16) * EE;
#pragma unroll
    for (int rg = 0; rg < 4; ++rg) {
#pragma unroll
      for (int n2 = 0; n2 < 2; ++n2) {
        int e = (h * 2 + n2) * 16 + fl;
        obt[(g * 4 + rg) * EE + e] = oacc[n2][rg] * inv[rg];
      }
    }
  }
}

extern "C" void kernel_launch(void* const* d_in, const int* in_sizes, int n_in,
                              void* d_out, int out_size, void* d_ws,
                              size_t ws_size, hipStream_t stream) {
  (void)in_sizes;
  (void)n_in;
  (void)out_size;
  (void)ws_size;
  const float* q = (const float*)d_in[0];
  const float* k = (const float*)d_in[1];
  const float* v = (const float*)d_in[2];
  const float* P = (const float*)d_in[3];
  float* out = (float*)d_out;

  float* kv_part = (float*)d_ws;                    // 256*16384 f32 = 16 MB
  float* ksum_part = kv_part + 256 * 16384;         // 256*256 f32
  _Float16* kvt_g = (_Float16*)(ksum_part + 256 * 256);  // 32*16384 f16
  float* ksum_g = (float*)(kvt_g + 32 * 16384);          // 32*256 f32

  hipLaunchKernelGGL(fa_kside, dim3(BH * SPLITS), dim3(1024), 0, stream, k, v,
                     P, kv_part, ksum_part);
  hipLaunchKernelGGL(fa_reduce, dim3(544), dim3(256), 0, stream, kv_part,
                     ksum_part, kvt_g, ksum_g);
  hipLaunchKernelGGL(fa_qside, dim3(BH * QB), dim3(1024), 0, stream, q, P,
                     kvt_g, ksum_g, out);
}